// Round 2
// baseline (752.509 us; speedup 1.0000x reference)
//
#include <hip/hip_runtime.h>
#include <stdint.h>

#define NN 8192
#define FD 256
#define LOG2E 1.44269504088896340736f

typedef __attribute__((ext_vector_type(8))) __bf16 bf16x8;
typedef __attribute__((ext_vector_type(4))) float f32x4;

__device__ __forceinline__ unsigned short f2bf(float x) {
    unsigned u = __float_as_uint(x);
    u = u + 0x7fffu + ((u >> 16) & 1u);   // RNE; no NaNs in this problem
    return (unsigned short)(u >> 16);
}
__device__ __forceinline__ bf16x8 ld_bf8(const unsigned short* p) {
    uint4 v = *(const uint4*)p;
    return __builtin_bit_cast(bf16x8, v);
}

// ---------------- Kernel 0: WbT[f][k] = bf16(W[k][f]) ----------------
__global__ __launch_bounds__(256) void wtrans_kernel(const float* __restrict__ W,
                                                     unsigned short* __restrict__ WbT) {
    int idx = blockIdx.x * 256 + threadIdx.x;   // 65536 elems
    int k = idx >> 8, f = idx & 255;
    WbT[f * 256 + k] = f2bf(W[idx]);
}

// ---------------- Kernel 1: WhT[f][i] = bf16((h@W+b)[i][f]); fused f1/f2 ----------------
// MFMA 16x16x32 bf16. Block = 256 thr (4 waves), tile = 32 rows x 256 cols, K=256.
__global__ __launch_bounds__(256) void gemm1_kernel(const float* __restrict__ h,
                                                    const unsigned short* __restrict__ WbT,
                                                    const float* __restrict__ bias,
                                                    const float* __restrict__ av,
                                                    unsigned short* __restrict__ WhT,
                                                    float* __restrict__ f1p,
                                                    float* __restrict__ f2p) {
    __shared__ float Wh_s[256 * 33];   // [f][i], +1 pad
    __shared__ float red_s[2 * 8 * 32];
    int t = threadIdx.x;
    int l = t & 63, w = t >> 6;
    int i0 = blockIdx.x * 32;
    int fbase = w * 64;
    int cl = l & 15, q = l >> 4;

    f32x4 acc[2][4] = {};
    const float* hA0 = h + (size_t)(i0 + cl) * FD;
    const float* hA1 = h + (size_t)(i0 + 16 + cl) * FD;

    #pragma unroll
    for (int ks = 0; ks < 8; ++ks) {
        int kk = ks * 32 + q * 8;
        union { unsigned short u[8]; bf16x8 v; } ua0, ua1;
        float4 x0 = *(const float4*)(hA0 + kk);
        float4 x1 = *(const float4*)(hA0 + kk + 4);
        float4 y0 = *(const float4*)(hA1 + kk);
        float4 y1 = *(const float4*)(hA1 + kk + 4);
        ua0.u[0]=f2bf(x0.x); ua0.u[1]=f2bf(x0.y); ua0.u[2]=f2bf(x0.z); ua0.u[3]=f2bf(x0.w);
        ua0.u[4]=f2bf(x1.x); ua0.u[5]=f2bf(x1.y); ua0.u[6]=f2bf(x1.z); ua0.u[7]=f2bf(x1.w);
        ua1.u[0]=f2bf(y0.x); ua1.u[1]=f2bf(y0.y); ua1.u[2]=f2bf(y0.z); ua1.u[3]=f2bf(y0.w);
        ua1.u[4]=f2bf(y1.x); ua1.u[5]=f2bf(y1.y); ua1.u[6]=f2bf(y1.z); ua1.u[7]=f2bf(y1.w);
        #pragma unroll
        for (int bg = 0; bg < 4; ++bg) {
            bf16x8 bF = ld_bf8(WbT + (fbase + bg * 16 + cl) * 256 + kk);
            acc[0][bg] = __builtin_amdgcn_mfma_f32_16x16x32_bf16(ua0.v, bF, acc[0][bg], 0, 0, 0);
            acc[1][bg] = __builtin_amdgcn_mfma_f32_16x16x32_bf16(ua1.v, bF, acc[1][bg], 0, 0, 0);
        }
    }

    // C layout: col = lane&15, row = (lane>>4)*4 + reg   [m89-verified]
    #pragma unroll
    for (int mt = 0; mt < 2; ++mt)
        #pragma unroll
        for (int bg = 0; bg < 4; ++bg)
            #pragma unroll
            for (int e = 0; e < 4; ++e) {
                int il = mt * 16 + q * 4 + e;
                int fl = fbase + bg * 16 + cl;
                Wh_s[fl * 33 + il] = acc[mt][bg][e] + bias[fl];
            }
    __syncthreads();
    {   // thread t owns f-row t; write 32 bf16 (i-contig) as 4x uint4
        const float* src = &Wh_s[t * 33];
        unsigned short* dst = WhT + (size_t)t * NN + i0;
        #pragma unroll
        for (int ig = 0; ig < 4; ++ig) {
            union { unsigned short u[8]; uint4 v; } p;
            #pragma unroll
            for (int e = 0; e < 8; ++e) p.u[e] = f2bf(src[ig * 8 + e]);
            *(uint4*)(dst + ig * 8) = p.v;
        }
    }
    // fused f1/f2 partials: thread t -> i = t&31, f-chunk = t>>5 (32 f's)
    {
        int i = t & 31, fc = t >> 5;
        float s1 = 0.f, s2 = 0.f;
        #pragma unroll
        for (int fo = 0; fo < 32; ++fo) {
            int f = fc * 32 + fo;
            float wv = Wh_s[f * 33 + i];
            s1 += wv * av[f];
            s2 += wv * av[256 + f];
        }
        red_s[fc * 32 + i] = s1;
        red_s[256 + fc * 32 + i] = s2;
    }
    __syncthreads();
    if (t < 32) {
        float s = 0.f;
        #pragma unroll
        for (int fc = 0; fc < 8; ++fc) s += red_s[fc * 32 + t];
        f1p[i0 + t] = s * LOG2E;
    } else if (t < 64) {
        int i = t - 32;
        float s = 0.f;
        #pragma unroll
        for (int fc = 0; fc < 8; ++fc) s += red_s[256 + fc * 32 + i];
        f2p[i0 + i] = s * LOG2E;
    }
}

// ---------------- Kernel 2: fused masked-softmax attention x Wh — barrier-free ----------------
// Grid 512 blocks x 256 thr. Wave = 16 rows x 64 f-cols (w = f-slice). Each wave loops all
// 8192 j in k=32 chunks: computes its P A-fragment in registers (lane -> row cl, cols q*8..+7),
// 4 MFMAs vs WhT B-frags. No LDS, no __syncthreads. adj/f2: depth-4 reg prefetch; B: depth-1.
__global__ __launch_bounds__(256, 2) void gat_kernel(const int* __restrict__ adj,
                                                     const unsigned short* __restrict__ WhT,
                                                     const float* __restrict__ f1p,
                                                     const float* __restrict__ f2p,
                                                     float* __restrict__ out) {
    int t = threadIdx.x;
    int l = t & 63, w = t >> 6;         // w = f-slice 0..3
    int i0 = blockIdx.x * 16;
    int cl = l & 15, q = l >> 4;
    int fbase = w * 64;

    float f1v = f1p[i0 + cl];
    const int* arow = adj + (size_t)(i0 + cl) * NN + q * 8;
    const float* f2row = f2p + q * 8;
    const unsigned short* wrow = WhT + (size_t)(fbase + cl) * NN + q * 8;

    f32x4 acc[4] = {};
    float rs = 0.f;

    // depth-4 adj/f2 prefetch queues (each chunk = 8 ints + 8 floats per lane)
    int4   aq[4][2];
    float4 fq[4][2];
    #pragma unroll
    for (int p = 0; p < 4; ++p) {
        aq[p][0] = *(const int4*)(arow + p * 32);
        aq[p][1] = *(const int4*)(arow + p * 32 + 4);
        fq[p][0] = *(const float4*)(f2row + p * 32);
        fq[p][1] = *(const float4*)(f2row + p * 32 + 4);
    }
    bf16x8 bcur[4];
    #pragma unroll
    for (int bg = 0; bg < 4; ++bg) bcur[bg] = ld_bf8(wrow + (size_t)bg * 16 * NN);

    #pragma unroll 4
    for (int jt = 0; jt < NN / 32; ++jt) {
        int slot = jt & 3;
        int4 a0 = aq[slot][0], a1 = aq[slot][1];
        float4 F0 = fq[slot][0], F1 = fq[slot][1];

        // prefetch adj/f2 for jt+4 (clamped re-load on tail, values unused)
        int pj = jt + 4 < NN / 32 ? jt + 4 : jt;
        aq[slot][0] = *(const int4*)(arow + pj * 32);
        aq[slot][1] = *(const int4*)(arow + pj * 32 + 4);
        fq[slot][0] = *(const float4*)(f2row + pj * 32);
        fq[slot][1] = *(const float4*)(f2row + pj * 32 + 4);

        // prefetch B for jt+1
        int bj = jt + 1 < NN / 32 ? jt + 1 : jt;
        bf16x8 bnext[4];
        #pragma unroll
        for (int bg = 0; bg < 4; ++bg)
            bnext[bg] = ld_bf8(wrow + (size_t)bg * 16 * NN + bj * 32);

        // P fragment: lane -> row cl, cols jt*32 + q*8 + e  (== MFMA A-layout)
        float fa[8] = {F0.x, F0.y, F0.z, F0.w, F1.x, F1.y, F1.z, F1.w};
        int   ad[8] = {a0.x, a0.y, a0.z, a0.w, a1.x, a1.y, a1.z, a1.w};
        union { unsigned short u[8]; bf16x8 v; } af;
        #pragma unroll
        for (int e = 0; e < 8; ++e) {
            float s = f1v + fa[e];
            s = fmaxf(s, 0.2f * s);          // leaky_relu (slope 0.2), pre-scaled by log2e
            float wv = exp2f(s);
            wv = ad[e] > 0 ? wv : 0.f;
            rs += wv;
            af.u[e] = f2bf(wv);
        }
        #pragma unroll
        for (int bg = 0; bg < 4; ++bg)
            acc[bg] = __builtin_amdgcn_mfma_f32_16x16x32_bf16(af.v, bcur[bg], acc[bg], 0, 0, 0);
        #pragma unroll
        for (int bg = 0; bg < 4; ++bg) bcur[bg] = bnext[bg];
    }

    // rowsum: lanes {cl, cl+16, cl+32, cl+48} hold partials for row cl
    rs += __shfl_xor(rs, 16);
    rs += __shfl_xor(rs, 32);
    // epilogue: C layout row = q*4+e, col = cl
    #pragma unroll
    for (int e = 0; e < 4; ++e) {
        int r = q * 4 + e;
        float inv = 1.0f / __shfl(rs, r);
        #pragma unroll
        for (int bg = 0; bg < 4; ++bg)
            out[(size_t)(i0 + r) * FD + fbase + bg * 16 + cl] = acc[bg][e] * inv;
    }
}

extern "C" void kernel_launch(void* const* d_in, const int* in_sizes, int n_in,
                              void* d_out, int out_size, void* d_ws, size_t ws_size,
                              hipStream_t stream) {
    const float* h   = (const float*)d_in[0];
    const int*   adj = (const int*)d_in[1];
    const float* W   = (const float*)d_in[2];
    const float* b   = (const float*)d_in[3];
    const float* a   = (const float*)d_in[4];
    float* out = (float*)d_out;

    char* ws = (char*)d_ws;
    unsigned short* WhT = (unsigned short*)ws;                        // 256 x 8192 bf16 = 4 MB
    unsigned short* WbT = (unsigned short*)(ws + 4 * 1024 * 1024);    // 256 x 256 bf16 = 128 KB
    float* f1p = (float*)(ws + 4 * 1024 * 1024 + 128 * 1024);         // 8192 f32
    float* f2p = f1p + NN;                                            // 8192 f32

    wtrans_kernel<<<256, 256, 0, stream>>>(W, WbT);
    gemm1_kernel<<<256, 256, 0, stream>>>(h, WbT, b, a, WhT, f1p, f2p);
    gat_kernel<<<512, 256, 0, stream>>>(adj, WhT, f1p, f2p, out);
}

// Round 3
// 503.707 us; speedup vs baseline: 1.4939x; 1.4939x over previous
//
#include <hip/hip_runtime.h>
#include <stdint.h>

#define NN 8192
#define FD 256
#define LOG2E 1.44269504088896340736f
#define SPLIT 4
#define JSLICE (NN / SPLIT)      // 2048
#define JCH 32                   // j per chunk (K per MFMA phase)
#define NCH (JSLICE / JCH)       // 64 chunks per block
#define PST 40                   // P_s row stride in elems (80 B -> 2-way-max bank phase, free)

typedef __attribute__((ext_vector_type(8))) __bf16 bf16x8;
typedef __attribute__((ext_vector_type(4))) float f32x4;

__device__ __forceinline__ unsigned short f2bf(float x) {
    unsigned u = __float_as_uint(x);
    u = u + 0x7fffu + ((u >> 16) & 1u);   // RNE; no NaNs in this problem
    return (unsigned short)(u >> 16);
}
__device__ __forceinline__ bf16x8 ld_bf8(const unsigned short* p) {
    uint4 v = *(const uint4*)p;
    return __builtin_bit_cast(bf16x8, v);
}
// Non-sinkable async global->LDS, 16 B/lane. LDS ptr must be wave-uniform.
__device__ __forceinline__ void async_ld16(const int* g, int* lds_base) {
    __builtin_amdgcn_global_load_lds(
        (const __attribute__((address_space(1))) void*)g,
        (__attribute__((address_space(3))) void*)lds_base, 16, 0, 0);
}

// ---------------- Kernel 0: WbT[f][k] = bf16(W[k][f]) ----------------
__global__ __launch_bounds__(256) void wtrans_kernel(const float* __restrict__ W,
                                                     unsigned short* __restrict__ WbT) {
    int idx = blockIdx.x * 256 + threadIdx.x;   // 65536 elems
    int k = idx >> 8, f = idx & 255;
    WbT[f * 256 + k] = f2bf(W[idx]);
}

// ---------------- Kernel 1: WhT[f][i] = bf16((h@W+b)[i][f]); fused f1/f2 ----------------
__global__ __launch_bounds__(256) void gemm1_kernel(const float* __restrict__ h,
                                                    const unsigned short* __restrict__ WbT,
                                                    const float* __restrict__ bias,
                                                    const float* __restrict__ av,
                                                    unsigned short* __restrict__ WhT,
                                                    float* __restrict__ f1p,
                                                    float* __restrict__ f2p) {
    __shared__ float Wh_s[256 * 33];   // [f][i], +1 pad
    __shared__ float red_s[2 * 8 * 32];
    int t = threadIdx.x;
    int l = t & 63, w = t >> 6;
    int i0 = blockIdx.x * 32;
    int fbase = w * 64;
    int cl = l & 15, q = l >> 4;

    f32x4 acc[2][4] = {};
    const float* hA0 = h + (size_t)(i0 + cl) * FD;
    const float* hA1 = h + (size_t)(i0 + 16 + cl) * FD;

    #pragma unroll
    for (int ks = 0; ks < 8; ++ks) {
        int kk = ks * 32 + q * 8;
        union { unsigned short u[8]; bf16x8 v; } ua0, ua1;
        float4 x0 = *(const float4*)(hA0 + kk);
        float4 x1 = *(const float4*)(hA0 + kk + 4);
        float4 y0 = *(const float4*)(hA1 + kk);
        float4 y1 = *(const float4*)(hA1 + kk + 4);
        ua0.u[0]=f2bf(x0.x); ua0.u[1]=f2bf(x0.y); ua0.u[2]=f2bf(x0.z); ua0.u[3]=f2bf(x0.w);
        ua0.u[4]=f2bf(x1.x); ua0.u[5]=f2bf(x1.y); ua0.u[6]=f2bf(x1.z); ua0.u[7]=f2bf(x1.w);
        ua1.u[0]=f2bf(y0.x); ua1.u[1]=f2bf(y0.y); ua1.u[2]=f2bf(y0.z); ua1.u[3]=f2bf(y0.w);
        ua1.u[4]=f2bf(y1.x); ua1.u[5]=f2bf(y1.y); ua1.u[6]=f2bf(y1.z); ua1.u[7]=f2bf(y1.w);
        #pragma unroll
        for (int bg = 0; bg < 4; ++bg) {
            bf16x8 bF = ld_bf8(WbT + (fbase + bg * 16 + cl) * 256 + kk);
            acc[0][bg] = __builtin_amdgcn_mfma_f32_16x16x32_bf16(ua0.v, bF, acc[0][bg], 0, 0, 0);
            acc[1][bg] = __builtin_amdgcn_mfma_f32_16x16x32_bf16(ua1.v, bF, acc[1][bg], 0, 0, 0);
        }
    }

    // C layout: col = lane&15, row = (lane>>4)*4 + reg   [m89-verified]
    #pragma unroll
    for (int mt = 0; mt < 2; ++mt)
        #pragma unroll
        for (int bg = 0; bg < 4; ++bg)
            #pragma unroll
            for (int e = 0; e < 4; ++e) {
                int il = mt * 16 + q * 4 + e;
                int fl = fbase + bg * 16 + cl;
                Wh_s[fl * 33 + il] = acc[mt][bg][e] + bias[fl];
            }
    __syncthreads();
    {   // thread t owns f-row t; write 32 bf16 (i-contig) as 4x uint4
        const float* src = &Wh_s[t * 33];
        unsigned short* dst = WhT + (size_t)t * NN + i0;
        #pragma unroll
        for (int ig = 0; ig < 4; ++ig) {
            union { unsigned short u[8]; uint4 v; } p;
            #pragma unroll
            for (int e = 0; e < 8; ++e) p.u[e] = f2bf(src[ig * 8 + e]);
            *(uint4*)(dst + ig * 8) = p.v;
        }
    }
    // fused f1/f2 partials: thread t -> i = t&31, f-chunk = t>>5 (32 f's)
    {
        int i = t & 31, fc = t >> 5;
        float s1 = 0.f, s2 = 0.f;
        #pragma unroll
        for (int fo = 0; fo < 32; ++fo) {
            int f = fc * 32 + fo;
            float wv = Wh_s[f * 33 + i];
            s1 += wv * av[f];
            s2 += wv * av[256 + f];
        }
        red_s[fc * 32 + i] = s1;
        red_s[256 + fc * 32 + i] = s2;
    }
    __syncthreads();
    if (t < 32) {
        float s = 0.f;
        #pragma unroll
        for (int fc = 0; fc < 8; ++fc) s += red_s[fc * 32 + t];
        f1p[i0 + t] = s * LOG2E;
    } else if (t < 64) {
        int i = t - 32;
        float s = 0.f;
        #pragma unroll
        for (int fc = 0; fc < 8; ++fc) s += red_s[256 + fc * 32 + i];
        f2p[i0 + i] = s * LOG2E;
    }
}

// ---------------- Kernel 2: fused masked-softmax attention x Wh, j-split partials ----------------
// Grid = 256 strips x SPLIT j-slices; block = 256 thr (4 waves), 32 rows x 2048 j.
// Pipelined phases, ONE barrier each: async adj->LDS (dbuf, issued right after barrier,
// drained by the NEXT barrier = full phase of cover), P[jt] -> P_s[b], MFMA of P[jt-1] from
// P_s[!b] with B-frags register-prefetched one phase earlier. Rowsum in regs.
__global__ __launch_bounds__(256, 4) void gat_kernel(const int* __restrict__ adj,
                                                     const unsigned short* __restrict__ WhT,
                                                     const float* __restrict__ f1p,
                                                     const float* __restrict__ f2p,
                                                     float* __restrict__ num,
                                                     float* __restrict__ den) {
    __shared__ __align__(16) int adj_s[2][1024];             // [buf][wave*256 + lane*4], 32 rows x 32 j
    __shared__ __align__(16) unsigned short P_s[2][32 * PST];

    int t = threadIdx.x;
    int l = t & 63, w = t >> 6;
    int strip = blockIdx.x & 255;
    int s = blockIdx.x >> 8;                 // 0..SPLIT-1 (same-s blocks launch together -> L2 reuse of WhT slice)
    int i0 = strip * 32;
    int j0 = s * JSLICE;

    // P-compute mapping: lane owns row prow, 4 cols pcol..pcol+3 of each chunk
    int prow = w * 8 + (l >> 3);
    int pcol = (l & 7) * 4;
    float f1v = f1p[i0 + prow];
    const int* agl = adj + (size_t)(i0 + prow) * NN + j0 + pcol;   // lane's global adj addr

    // MFMA mapping: wave w -> f-slice
    int cl = l & 15, q = l >> 4;
    int fbase = w * 64;
    const unsigned short* wrowb = WhT + (size_t)(fbase + cl) * NN + j0 + q * 8;

    f32x4 acc[2][4] = {};
    float rs = 0.f;
    float4 f2n;
    bf16x8 bcur[4], bnext[4];

    // preload chunk 0
    async_ld16(agl, &adj_s[0][w * 256]);
    f2n = *(const float4*)(f2p + j0 + pcol);

    #pragma unroll 2
    for (int jt = 0; jt <= NCH; ++jt) {
        int b = jt & 1;
        __syncthreads();   // drains: adj_s[b] async load (issued last phase), B prefetch; orders P_s
        if (jt + 1 < NCH) async_ld16(agl + (jt + 1) * JCH, &adj_s[b ^ 1][w * 256]);

        if (jt < NCH) {
            int4 a4 = *(const int4*)&adj_s[b][t * 4];    // own lane's 4 adj ints
            float4 fv = f2n;
            if (jt + 1 < NCH) f2n = *(const float4*)(f2p + j0 + (jt + 1) * JCH + pcol);
            float fa[4] = {fv.x, fv.y, fv.z, fv.w};
            int ad[4] = {a4.x, a4.y, a4.z, a4.w};
            unsigned short pu[4];
            #pragma unroll
            for (int e = 0; e < 4; ++e) {
                float sv = f1v + fa[e];
                sv = fmaxf(sv, 0.2f * sv);               // leaky_relu (pre-scaled by log2e)
                float wv = exp2f(sv);
                wv = ad[e] > 0 ? wv : 0.f;
                rs += wv;
                pu[e] = f2bf(wv);
            }
            *(uint2*)&P_s[b][prow * PST + pcol] =
                make_uint2((unsigned)pu[0] | ((unsigned)pu[1] << 16),
                           (unsigned)pu[2] | ((unsigned)pu[3] << 16));
            // B prefetch for chunk jt (consumed next phase); drained by next barrier
            #pragma unroll
            for (int bg = 0; bg < 4; ++bg)
                bnext[bg] = ld_bf8(wrowb + (size_t)bg * 16 * NN + jt * JCH);
        }
        if (jt > 0) {
            const unsigned short* ps = P_s[b ^ 1];
            bf16x8 af0 = ld_bf8(ps + cl * PST + q * 8);
            bf16x8 af1 = ld_bf8(ps + (16 + cl) * PST + q * 8);
            #pragma unroll
            for (int bg = 0; bg < 4; ++bg) {
                acc[0][bg] = __builtin_amdgcn_mfma_f32_16x16x32_bf16(af0, bcur[bg], acc[0][bg], 0, 0, 0);
                acc[1][bg] = __builtin_amdgcn_mfma_f32_16x16x32_bf16(af1, bcur[bg], acc[1][bg], 0, 0, 0);
            }
        }
        #pragma unroll
        for (int bg = 0; bg < 4; ++bg) bcur[bg] = bnext[bg];
    }

    // rowsum: 8 lanes (xor 1,2,4) share row prow
    rs += __shfl_xor(rs, 1);
    rs += __shfl_xor(rs, 2);
    rs += __shfl_xor(rs, 4);
    if ((l & 7) == 0) den[(size_t)s * NN + i0 + prow] = rs;

    // partial numerator: C layout row = q*4+e, col = cl
    float* nrow = num + (size_t)s * NN * FD;
    #pragma unroll
    for (int mt = 0; mt < 2; ++mt)
        #pragma unroll
        for (int e = 0; e < 4; ++e) {
            int r = mt * 16 + q * 4 + e;
            #pragma unroll
            for (int bg = 0; bg < 4; ++bg)
                nrow[(size_t)(i0 + r) * FD + fbase + bg * 16 + cl] = acc[mt][bg][e];
        }
}

// ---------------- Kernel 3: combine j-split partials ----------------
__global__ __launch_bounds__(256) void combine_kernel(const float* __restrict__ num,
                                                      const float* __restrict__ den,
                                                      float* __restrict__ out) {
    int idx = blockIdx.x * 256 + threadIdx.x;   // 2M elems; i = blockIdx (uniform per block)
    int i = idx >> 8;
    float nsum = 0.f, dsum = 0.f;
    #pragma unroll
    for (int s = 0; s < SPLIT; ++s) {
        nsum += num[(size_t)s * NN * FD + idx];
        dsum += den[(size_t)s * NN + i];
    }
    out[idx] = nsum / dsum;
}

extern "C" void kernel_launch(void* const* d_in, const int* in_sizes, int n_in,
                              void* d_out, int out_size, void* d_ws, size_t ws_size,
                              hipStream_t stream) {
    const float* h   = (const float*)d_in[0];
    const int*   adj = (const int*)d_in[1];
    const float* W   = (const float*)d_in[2];
    const float* b   = (const float*)d_in[3];
    const float* a   = (const float*)d_in[4];
    float* out = (float*)d_out;

    char* ws = (char*)d_ws;
    unsigned short* WhT = (unsigned short*)ws;                          // 4 MB
    unsigned short* WbT = (unsigned short*)(ws + (4u << 20));           // 128 KB
    float* f1p = (float*)(ws + (4u << 20) + (128u << 10));              // 32 KB
    float* f2p = f1p + NN;                                              // 32 KB
    float* den = f2p + NN;                                              // SPLIT*NN f32 = 128 KB
    float* num = (float*)(ws + (8u << 20));                             // SPLIT*8 MB = 32 MB

    wtrans_kernel<<<256, 256, 0, stream>>>(W, WbT);
    gemm1_kernel<<<256, 256, 0, stream>>>(h, WbT, b, a, WhT, f1p, f2p);
    gat_kernel<<<256 * SPLIT, 256, 0, stream>>>(adj, WhT, f1p, f2p, num, den);
    combine_kernel<<<NN * FD / 256, 256, 0, stream>>>(num, den, out);
}